// Round 7
// baseline (73.378 us; speedup 1.0000x reference)
//
#include <hip/hip_runtime.h>
#include <hip/hip_bf16.h>

// Problem constants: B=8, C=64, C8=8, H=128, W=128
#define BDIM 8
#define CDIM 64
#define C8DIM 8
#define HDIM 128
#define WDIM 128
#define HW (HDIM * WDIM)   // 16384

typedef short bf16x8 __attribute__((ext_vector_type(8)));
typedef float f32x4 __attribute__((ext_vector_type(4)));

// ---------------- bf16 helpers ----------------
__device__ inline unsigned pk_bf16(float a, float b) {
    unsigned ua = (unsigned)__bfloat16_as_ushort(__float2bfloat16(a));
    unsigned ub = (unsigned)__bfloat16_as_ushort(__float2bfloat16(b));
    return ua | (ub << 16);
}
__device__ inline void cvt2(unsigned u, float& lo, float& hi) {
    lo = __uint_as_float(u << 16);
    hi = __uint_as_float(u & 0xffff0000u);
}

// ---------------------------------------------------------------------------
// Kernel 1: fused QKV projection as MFMA GEMM + bf16 x+y residual tile.
//   D[o][p] = sum_c Wall[o][c] * X[c][p],  o in [0,80), c in [0,128)
// One block per (b, 128-position tile). 4 waves; wave covers 32 positions
// (2 n-tiles), all 5 m-tiles, K=128 as 2 pairs of (x-ch 32, y-ch 32).
// ALL global stores are coalesced via an LDS transpose of the output tile
// (smem is reused: weights during GEMM -> out-tile -> xy-tile, with barriers).
// C/D layout: col = lane&15 (p), row = (lane>>4)*4 + reg (o) [HW-verified].
// ---------------------------------------------------------------------------
__global__ __launch_bounds__(256) void qkv_kernel(
    const float* __restrict__ x, const float* __restrict__ y,
    const float* __restrict__ Wq, const float* __restrict__ bq,
    const float* __restrict__ Wk, const float* __restrict__ bk,
    const float* __restrict__ Wv, const float* __restrict__ bv,
    uint4* __restrict__ q_pm, uint4* __restrict__ k_pm, uint4* __restrict__ v_pm,
    uint4* __restrict__ xy_pm)
{
    // phase A: weights [80][128] bf16 swizzled (10240 ushort)
    // phase B: out-tile [128 pos][88] (11264 ushort; cols 0..7 q, 8..15 k, 16..79 v)
    // phase C: xy-tile  [128 pos][72] (9216 ushort; cols 0..63)
    __shared__ ushort smem[128 * 88];
    __shared__ float  sb[80];

    const int t = threadIdx.x;

    // ---- phase A: stage weights ----
    for (int i = t; i < 80 * 64; i += 256) {
        int o  = i >> 6;
        int cp = i & 63;
        int c  = cp * 2;
        float w0, w1;
        if (o < 8) {
            if (c < 64) { w0 = Wq[o * 64 + c]; w1 = Wq[o * 64 + c + 1]; }
            else        { w0 = 0.f; w1 = 0.f; }
        } else if (o < 16) {
            if (c >= 64) { w0 = Wk[(o - 8) * 64 + c - 64]; w1 = Wk[(o - 8) * 64 + c - 63]; }
            else         { w0 = 0.f; w1 = 0.f; }
        } else {
            w0 = Wv[(o - 16) * 128 + c];
            w1 = Wv[(o - 16) * 128 + c + 1];
        }
        ((unsigned*)smem)[o * 64 + (cp ^ ((o & 7) << 2))] = pk_bf16(w0, w1);
    }
    if (t < 80) {
        sb[t] = (t < 8) ? bq[t] : (t < 16) ? bk[t - 8] : bv[t - 16];
    }
    __syncthreads();

    const int blk = blockIdx.x;
    const int b   = blk & 7;
    const int p0  = (blk >> 3) << 7;    // position tile base

    const int wv = t >> 6, ln = t & 63, lg = ln >> 4, li = ln & 15;
    const int pcol0 = p0 + wv * 32 + li;   // this lane's n=0 position

    const float* xb = x + (size_t)b * CDIM * HW;
    const float* yb = y + (size_t)b * CDIM * HW;

    f32x4 acc[5][2];
    #pragma unroll
    for (int mt = 0; mt < 5; mt++)
        #pragma unroll
        for (int n = 0; n < 2; n++) acc[mt][n] = (f32x4){0.f, 0.f, 0.f, 0.f};

    uint4 xys[2][2];   // packed bf16(x+y): [pair][n] = ch pair*32+lg*8 .. +7

    #pragma unroll
    for (int pair = 0; pair < 2; pair++) {
        const int chb = pair * 32 + lg * 8;          // x/y channel base
        const float* xp = xb + (size_t)chb * HW;
        const float* yp = yb + (size_t)chb * HW;
        bf16x8 bx[2], by[2];
        #pragma unroll
        for (int n = 0; n < 2; n++) {
            const size_t poff = (size_t)(pcol0 + n * 16);
            float fx[8], fy[8];
            #pragma unroll
            for (int e = 0; e < 8; e++) {
                fx[e] = xp[(size_t)e * HW + poff];
                fy[e] = yp[(size_t)e * HW + poff];
            }
            uint4 ux, uy, s;
            ux.x = pk_bf16(fx[0], fx[1]); ux.y = pk_bf16(fx[2], fx[3]);
            ux.z = pk_bf16(fx[4], fx[5]); ux.w = pk_bf16(fx[6], fx[7]);
            uy.x = pk_bf16(fy[0], fy[1]); uy.y = pk_bf16(fy[2], fy[3]);
            uy.z = pk_bf16(fy[4], fy[5]); uy.w = pk_bf16(fy[6], fy[7]);
            s.x = pk_bf16(fx[0] + fy[0], fx[1] + fy[1]);
            s.y = pk_bf16(fx[2] + fy[2], fx[3] + fy[3]);
            s.z = pk_bf16(fx[4] + fy[4], fx[5] + fy[5]);
            s.w = pk_bf16(fx[6] + fy[6], fx[7] + fy[7]);
            bx[n] = *(bf16x8*)&ux;
            by[n] = *(bf16x8*)&uy;
            xys[pair][n] = s;
        }
        #pragma unroll
        for (int mt = 0; mt < 5; mt++) {
            const int row = mt * 16 + li;
            const int sw  = ((li & 7) << 3);
            bf16x8 ax = *(const bf16x8*)&smem[row * 128 + ((pair * 32 + lg * 8) ^ sw)];
            bf16x8 ay = *(const bf16x8*)&smem[row * 128 + (((2 + pair) * 32 + lg * 8) ^ sw)];
            #pragma unroll
            for (int n = 0; n < 2; n++) {
                acc[mt][n] = __builtin_amdgcn_mfma_f32_16x16x32_bf16(ax, bx[n], acc[mt][n], 0, 0, 0);
                acc[mt][n] = __builtin_amdgcn_mfma_f32_16x16x32_bf16(ay, by[n], acc[mt][n], 0, 0, 0);
            }
        }
    }
    __syncthreads();   // weights dead; smem becomes out-tile

    // ---- phase B: out-tile [pl][88] -> coalesced q/k/v stores ----
    #pragma unroll
    for (int mt = 0; mt < 5; mt++) {
        const int ob = mt * 16 + lg * 4;
        const float b0 = sb[ob + 0], b1 = sb[ob + 1], b2 = sb[ob + 2], b3 = sb[ob + 3];
        #pragma unroll
        for (int n = 0; n < 2; n++) {
            const int pl = wv * 32 + n * 16 + li;
            uint2 w;
            w.x = pk_bf16(acc[mt][n][0] + b0, acc[mt][n][1] + b1);
            w.y = pk_bf16(acc[mt][n][2] + b2, acc[mt][n][3] + b3);
            *(uint2*)&smem[pl * 88 + ob] = w;
        }
    }
    __syncthreads();

    const size_t gpb = (size_t)b * HW + p0;
    if (t < 128) {
        q_pm[gpb + t] = *(const uint4*)&smem[t * 88 + 0];
    } else {
        k_pm[gpb + (t - 128)] = *(const uint4*)&smem[(t - 128) * 88 + 8];
    }
    #pragma unroll
    for (int i2 = 0; i2 < 4; i2++) {
        const int f = t + i2 * 256;        // 0..1023 over 128 pos x 8 uint4
        const int p = f >> 3, q8 = f & 7;
        v_pm[(gpb + p) * 8 + q8] = *(const uint4*)&smem[p * 88 + 16 + q8 * 8];
    }

    if (xy_pm) {
        __syncthreads();   // smem becomes xy-tile [pl][72]
        #pragma unroll
        for (int pair = 0; pair < 2; pair++)
            #pragma unroll
            for (int n = 0; n < 2; n++) {
                const int pl = wv * 32 + n * 16 + li;
                *(uint4*)&smem[pl * 72 + pair * 32 + lg * 8] = xys[pair][n];
            }
        __syncthreads();
        #pragma unroll
        for (int i2 = 0; i2 < 4; i2++) {
            const int f = t + i2 * 256;
            const int p = f >> 3, q8 = f & 7;
            xy_pm[(gpb + p) * 8 + q8] = *(const uint4*)&smem[p * 72 + q8 * 8];
        }
    }
}

// ---------------------------------------------------------------------------
// Kernel 2 (column branch): one block per (b, c).  MFMA tile-GEMMs:
//   QK^T (swapped): D[j][i] = sum_ch K[j][ch] * Q[ch][i]
//   per-row (i) softmax with diag mask, unnormalized
//   PV: D2[ch][i] = sum_j V[ch][j] * P[j][i]
// Writes: H_t[b][row=i][col=cc][ch] bf16 (uint2 stores), mH[b][cc][i], sH.
// ---------------------------------------------------------------------------
__global__ __launch_bounds__(256, 2) void colattn_kernel(
    const uint4* __restrict__ q_pm, const uint4* __restrict__ k_pm,
    const uint4* __restrict__ v_pm,
    ushort* __restrict__ H_t, float* __restrict__ mH_g, float* __restrict__ sH_g)
{
    __shared__ ushort Q_lds[128 * 8];     // [i][ch]
    __shared__ ushort K_lds[128 * 8];     // [j][ch]
    __shared__ ushort V_lds[64 * 136];    // [ch][j], pad 8
    __shared__ ushort P_lds[128 * 136];   // [i][j], pad 8

    const int blk = blockIdx.x;
    const int b  = blk & 7;
    const int cc = blk >> 3;
    const int t  = threadIdx.x;

    if (t < 128) {
        *(uint4*)&Q_lds[t * 8] = q_pm[(size_t)b * HW + (size_t)t * 128 + cc];
    } else {
        int j = t - 128;
        *(uint4*)&K_lds[j * 8] = k_pm[(size_t)b * HW + (size_t)j * 128 + cc];
    }
    {
        int j = t & 127, h = t >> 7;
        const uint4* vp = v_pm + ((size_t)b * HW + (size_t)j * 128 + cc) * 8 + 4 * h;
        #pragma unroll
        for (int qd = 0; qd < 4; qd++) {
            uint4 vu = vp[qd];
            int ch0 = 32 * h + 8 * qd;
            V_lds[(ch0 + 0) * 136 + j] = (ushort)(vu.x & 0xffff);
            V_lds[(ch0 + 1) * 136 + j] = (ushort)(vu.x >> 16);
            V_lds[(ch0 + 2) * 136 + j] = (ushort)(vu.y & 0xffff);
            V_lds[(ch0 + 3) * 136 + j] = (ushort)(vu.y >> 16);
            V_lds[(ch0 + 4) * 136 + j] = (ushort)(vu.z & 0xffff);
            V_lds[(ch0 + 5) * 136 + j] = (ushort)(vu.z >> 16);
            V_lds[(ch0 + 6) * 136 + j] = (ushort)(vu.w & 0xffff);
            V_lds[(ch0 + 7) * 136 + j] = (ushort)(vu.w >> 16);
        }
    }
    __syncthreads();

    const int wv = t >> 6, ln = t & 63, lg = ln >> 4, li = ln & 15;
    const bf16x8 zf = {0, 0, 0, 0, 0, 0, 0, 0};

    // ---- QK^T ----
    bf16x8 afr[8], bfr[2];
    #pragma unroll
    for (int jt = 0; jt < 8; jt++)
        afr[jt] = (lg == 0) ? *(const bf16x8*)&K_lds[(jt * 16 + li) * 8] : zf;
    #pragma unroll
    for (int it2 = 0; it2 < 2; it2++)
        bfr[it2] = (lg == 0) ? *(const bf16x8*)&Q_lds[((2 * wv + it2) * 16 + li) * 8] : zf;

    f32x4 dfr[2][8];
    #pragma unroll
    for (int a = 0; a < 2; a++)
        #pragma unroll
        for (int jt = 0; jt < 8; jt++) dfr[a][jt] = (f32x4){0.f, 0.f, 0.f, 0.f};

    #pragma unroll
    for (int it2 = 0; it2 < 2; it2++)
        #pragma unroll
        for (int jt = 0; jt < 8; jt++)
            dfr[it2][jt] = __builtin_amdgcn_mfma_f32_16x16x32_bf16(
                afr[jt], bfr[it2], dfr[it2][jt], 0, 0, 0);

    // ---- softmax (unnormalized, diag masked) ----
    #pragma unroll
    for (int it2 = 0; it2 < 2; it2++) {
        const int i = (2 * wv + it2) * 16 + li;
        float m = -1e30f;
        #pragma unroll
        for (int jt = 0; jt < 8; jt++)
            #pragma unroll
            for (int rr = 0; rr < 4; rr++) {
                int j = jt * 16 + lg * 4 + rr;
                float e = dfr[it2][jt][rr];
                if (j == i) e = -1e30f;
                dfr[it2][jt][rr] = e;
                m = fmaxf(m, e);
            }
        m = fmaxf(m, __shfl_xor(m, 16));
        m = fmaxf(m, __shfl_xor(m, 32));
        float s = 0.f;
        #pragma unroll
        for (int jt = 0; jt < 8; jt++)
            #pragma unroll
            for (int rr = 0; rr < 4; rr++) {
                float p = __expf(dfr[it2][jt][rr] - m);
                dfr[it2][jt][rr] = p;
                s += p;
            }
        s += __shfl_xor(s, 16);
        s += __shfl_xor(s, 32);
        #pragma unroll
        for (int jt = 0; jt < 8; jt++) {
            uint2 w;
            w.x = pk_bf16(dfr[it2][jt][0], dfr[it2][jt][1]);
            w.y = pk_bf16(dfr[it2][jt][2], dfr[it2][jt][3]);
            *(uint2*)&P_lds[(size_t)i * 136 + jt * 16 + lg * 4] = w;
        }
        if (lg == 0) {
            mH_g[((size_t)b * 128 + cc) * 128 + i] = m;
            sH_g[((size_t)b * 128 + cc) * 128 + i] = s;
        }
    }
    __syncthreads();

    // ---- PV ----
    f32x4 ofr[8];
    #pragma unroll
    for (int itl = 0; itl < 8; itl++) ofr[itl] = (f32x4){0.f, 0.f, 0.f, 0.f};

    #pragma unroll
    for (int ks = 0; ks < 4; ks++) {
        const int jb = ks * 32 + lg * 8;
        bf16x8 av = *(const bf16x8*)&V_lds[(wv * 16 + li) * 136 + jb];
        #pragma unroll
        for (int itl = 0; itl < 8; itl++) {
            bf16x8 bp = *(const bf16x8*)&P_lds[(itl * 16 + li) * 136 + jb];
            ofr[itl] = __builtin_amdgcn_mfma_f32_16x16x32_bf16(av, bp, ofr[itl], 0, 0, 0);
        }
    }

    // ---- store H_t[b][row=i][col=cc][ch], 8B per (itl) ----
    #pragma unroll
    for (int itl = 0; itl < 8; itl++) {
        const int i = itl * 16 + li;
        uint2 w;
        w.x = pk_bf16(ofr[itl][0], ofr[itl][1]);
        w.y = pk_bf16(ofr[itl][2], ofr[itl][3]);
        *(uint2*)&H_t[(((size_t)b * 128 + i) * 128 + cc) * 64 + wv * 16 + lg * 4] = w;
    }
}

// ---------------------------------------------------------------------------
// Kernel 3 (row branch + merge): one block per (b, r).  Same GEMM structure
// (no diag mask); epilogue merges with the column branch (mH/sH/H_t) and adds
// the residual:  out = (H*wH + W*wW) * gamma/(sH*wH + sW*wW) + (x + y).
// USE_XY: residual from bf16 xy_pm (written by qkv) instead of fp32 x,y.
// ---------------------------------------------------------------------------
template<int USE_XY>
__global__ __launch_bounds__(256, 2) void rowattn_kernel(
    const uint4* __restrict__ q_pm, const uint4* __restrict__ k_pm,
    const uint4* __restrict__ v_pm,
    const ushort* __restrict__ H_t, const float* __restrict__ mH_g,
    const float* __restrict__ sH_g,
    const float* __restrict__ x, const float* __restrict__ y,
    const ushort* __restrict__ xy_pm,
    const float* __restrict__ gptr, float* __restrict__ out)
{
    __shared__ ushort Q_lds[128 * 8];     // [i][ch]  (i = column index)
    __shared__ ushort K_lds[128 * 8];     // [j][ch]
    __shared__ ushort V_lds[64 * 136];    // [ch][j]
    __shared__ ushort P_lds[128 * 136];   // [i][j]
    __shared__ float mW_s[128], sW_s[128];

    const int blk = blockIdx.x;
    const int b = blk & 7;
    const int r = blk >> 3;
    const int t = threadIdx.x;

    if (t < 128) {
        *(uint4*)&Q_lds[t * 8] = q_pm[(size_t)b * HW + (size_t)r * 128 + t];
    } else {
        int j = t - 128;
        *(uint4*)&K_lds[j * 8] = k_pm[(size_t)b * HW + (size_t)r * 128 + j];
    }
    {
        int j = t & 127, h = t >> 7;
        const uint4* vp = v_pm + ((size_t)b * HW + (size_t)r * 128 + j) * 8 + 4 * h;
        #pragma unroll
        for (int qd = 0; qd < 4; qd++) {
            uint4 vu = vp[qd];
            int ch0 = 32 * h + 8 * qd;
            V_lds[(ch0 + 0) * 136 + j] = (ushort)(vu.x & 0xffff);
            V_lds[(ch0 + 1) * 136 + j] = (ushort)(vu.x >> 16);
            V_lds[(ch0 + 2) * 136 + j] = (ushort)(vu.y & 0xffff);
            V_lds[(ch0 + 3) * 136 + j] = (ushort)(vu.y >> 16);
            V_lds[(ch0 + 4) * 136 + j] = (ushort)(vu.z & 0xffff);
            V_lds[(ch0 + 5) * 136 + j] = (ushort)(vu.z >> 16);
            V_lds[(ch0 + 6) * 136 + j] = (ushort)(vu.w & 0xffff);
            V_lds[(ch0 + 7) * 136 + j] = (ushort)(vu.w >> 16);
        }
    }
    __syncthreads();

    const int wv = t >> 6, ln = t & 63, lg = ln >> 4, li = ln & 15;
    const bf16x8 zf = {0, 0, 0, 0, 0, 0, 0, 0};

    bf16x8 afr[8], bfr[2];
    #pragma unroll
    for (int jt = 0; jt < 8; jt++)
        afr[jt] = (lg == 0) ? *(const bf16x8*)&K_lds[(jt * 16 + li) * 8] : zf;
    #pragma unroll
    for (int it2 = 0; it2 < 2; it2++)
        bfr[it2] = (lg == 0) ? *(const bf16x8*)&Q_lds[((2 * wv + it2) * 16 + li) * 8] : zf;

    f32x4 dfr[2][8];
    #pragma unroll
    for (int a = 0; a < 2; a++)
        #pragma unroll
        for (int jt = 0; jt < 8; jt++) dfr[a][jt] = (f32x4){0.f, 0.f, 0.f, 0.f};

    #pragma unroll
    for (int it2 = 0; it2 < 2; it2++)
        #pragma unroll
        for (int jt = 0; jt < 8; jt++)
            dfr[it2][jt] = __builtin_amdgcn_mfma_f32_16x16x32_bf16(
                afr[jt], bfr[it2], dfr[it2][jt], 0, 0, 0);

    #pragma unroll
    for (int it2 = 0; it2 < 2; it2++) {
        const int i = (2 * wv + it2) * 16 + li;
        float m = -1e30f;
        #pragma unroll
        for (int jt = 0; jt < 8; jt++)
            #pragma unroll
            for (int rr = 0; rr < 4; rr++)
                m = fmaxf(m, dfr[it2][jt][rr]);
        m = fmaxf(m, __shfl_xor(m, 16));
        m = fmaxf(m, __shfl_xor(m, 32));
        float s = 0.f;
        #pragma unroll
        for (int jt = 0; jt < 8; jt++)
            #pragma unroll
            for (int rr = 0; rr < 4; rr++) {
                float p = __expf(dfr[it2][jt][rr] - m);
                dfr[it2][jt][rr] = p;
                s += p;
            }
        s += __shfl_xor(s, 16);
        s += __shfl_xor(s, 32);
        #pragma unroll
        for (int jt = 0; jt < 8; jt++) {
            uint2 w;
            w.x = pk_bf16(dfr[it2][jt][0], dfr[it2][jt][1]);
            w.y = pk_bf16(dfr[it2][jt][2], dfr[it2][jt][3]);
            *(uint2*)&P_lds[(size_t)i * 136 + jt * 16 + lg * 4] = w;
        }
        if (lg == 0) {
            mW_s[i] = m;
            sW_s[i] = s;
        }
    }
    __syncthreads();

    f32x4 ofr[8];
    #pragma unroll
    for (int itl = 0; itl < 8; itl++) ofr[itl] = (f32x4){0.f, 0.f, 0.f, 0.f};

    #pragma unroll
    for (int ks = 0; ks < 4; ks++) {
        const int jb = ks * 32 + lg * 8;
        bf16x8 av = *(const bf16x8*)&V_lds[(wv * 16 + li) * 136 + jb];
        #pragma unroll
        for (int itl = 0; itl < 8; itl++) {
            bf16x8 bp = *(const bf16x8*)&P_lds[(itl * 16 + li) * 136 + jb];
            ofr[itl] = __builtin_amdgcn_mfma_f32_16x16x32_bf16(av, bp, ofr[itl], 0, 0, 0);
        }
    }

    const float gamma = gptr[0];
    #pragma unroll
    for (int itl = 0; itl < 8; itl++) {
        const int i = itl * 16 + li;     // column index of this position
        float mWv = mW_s[i], sWv = sW_s[i];
        float mHv = mH_g[((size_t)b * 128 + i) * 128 + r];
        float sHv = sH_g[((size_t)b * 128 + i) * 128 + r];
        float m  = fmaxf(mHv, mWv);
        float wH = __expf(mHv - m);
        float wW = __expf(mWv - m);
        float invg = gamma / (sHv * wH + sWv * wW);

        // coalesced-footprint H read: [b][r][i][ch], 8B per lane per itl
        uint2 hw = *(const uint2*)&H_t[(((size_t)b * 128 + r) * 128 + i) * 64 + wv * 16 + lg * 4];
        float h[4];
        cvt2(hw.x, h[0], h[1]);
        cvt2(hw.y, h[2], h[3]);

        float resid[4];
        if (USE_XY) {
            uint2 xu = *(const uint2*)&xy_pm[((size_t)b * HW + (size_t)r * 128 + i) * 64 + wv * 16 + lg * 4];
            cvt2(xu.x, resid[0], resid[1]);
            cvt2(xu.y, resid[2], resid[3]);
        }

        #pragma unroll
        for (int rr = 0; rr < 4; rr++) {
            const int ch = wv * 16 + lg * 4 + rr;
            size_t o = (((size_t)b * 64 + ch) * 128 + r) * 128 + i;
            float res = USE_XY ? resid[rr] : (x[o] + y[o]);
            out[o] = (h[rr] * wH + ofr[itl][rr] * wW) * invg + res;
        }
    }
}

// ---------------------------------------------------------------------------
extern "C" void kernel_launch(void* const* d_in, const int* in_sizes, int n_in,
                              void* d_out, int out_size, void* d_ws, size_t ws_size,
                              hipStream_t stream)
{
    const float* x     = (const float*)d_in[0];
    const float* y     = (const float*)d_in[1];
    const float* Wq    = (const float*)d_in[2];
    const float* bq    = (const float*)d_in[3];
    const float* Wk    = (const float*)d_in[4];
    const float* bk    = (const float*)d_in[5];
    const float* Wv    = (const float*)d_in[6];
    const float* bv    = (const float*)d_in[7];
    const float* gamma = (const float*)d_in[8];
    float* out = (float*)d_out;

    // Workspace: q 2MB | k 2MB | v 16MB | H_t 16MB | mH .5MB | sH .5MB | xy 16MB
    uint4*  q_pm = (uint4*)d_ws;                        // 131072 uint4
    uint4*  k_pm = q_pm + (size_t)BDIM * HW;            // 131072 uint4
    uint4*  v_pm = k_pm + (size_t)BDIM * HW;            // 1048576 uint4
    ushort* H_t  = (ushort*)(v_pm + (size_t)BDIM * HW * 8);      // 8388608 us
    float*  mH   = (float*)(H_t + (size_t)BDIM * HW * 64);
    float*  sH   = mH + (size_t)BDIM * HW;
    ushort* xy   = (ushort*)(sH + (size_t)BDIM * HW);            // 8388608 us
    size_t need  = (size_t)((char*)(xy + (size_t)BDIM * HW * 64) - (char*)d_ws);
    const bool use_xy = ws_size >= need;

    qkv_kernel<<<dim3(BDIM * HW / 128), dim3(256), 0, stream>>>(
        x, y, Wq, bq, Wk, bk, Wv, bv, q_pm, k_pm, v_pm,
        use_xy ? (uint4*)xy : (uint4*)nullptr);

    colattn_kernel<<<dim3(BDIM * WDIM), dim3(256), 0, stream>>>(
        q_pm, k_pm, v_pm, H_t, mH, sH);

    if (use_xy) {
        rowattn_kernel<1><<<dim3(BDIM * HDIM), dim3(256), 0, stream>>>(
            q_pm, k_pm, v_pm, H_t, mH, sH, x, y, xy, gamma, out);
    } else {
        rowattn_kernel<0><<<dim3(BDIM * HDIM), dim3(256), 0, stream>>>(
            q_pm, k_pm, v_pm, H_t, mH, sH, x, y, xy, gamma, out);
    }
}

// Round 8
// 66.565 us; speedup vs baseline: 1.1024x; 1.1024x over previous
//
#include <hip/hip_runtime.h>
#include <hip/hip_bf16.h>

// Problem constants: B=8, C=64, C8=8, H=128, W=128
#define BDIM 8
#define CDIM 64
#define C8DIM 8
#define HDIM 128
#define WDIM 128
#define HW (HDIM * WDIM)   // 16384

typedef short bf16x8 __attribute__((ext_vector_type(8)));
typedef float f32x4 __attribute__((ext_vector_type(4)));

// ---------------- bf16 helpers ----------------
__device__ inline unsigned pk_bf16(float a, float b) {
    unsigned ua = (unsigned)__bfloat16_as_ushort(__float2bfloat16(a));
    unsigned ub = (unsigned)__bfloat16_as_ushort(__float2bfloat16(b));
    return ua | (ub << 16);
}
__device__ inline void cvt2(unsigned u, float& lo, float& hi) {
    lo = __uint_as_float(u << 16);
    hi = __uint_as_float(u & 0xffff0000u);
}

// ---------------------------------------------------------------------------
// Kernel 1: fused QKV projection as MFMA GEMM + bf16 x+y residual tile.
// 512 blocks = (b, 2 consecutive 128-position tiles). Weights staged ONCE per
// block (sW stays live across tiles; sOut is a separate transpose buffer).
// Tile-1 loads are issued before tile-0's store phases so the LDS round-trip
// hides the HBM latency (T14 split).
// C/D layout: col = lane&15 (p), row = (lane>>4)*4 + reg (o) [HW-verified].
// ---------------------------------------------------------------------------
__global__ __launch_bounds__(256) void qkv_kernel(
    const float* __restrict__ x, const float* __restrict__ y,
    const float* __restrict__ Wq, const float* __restrict__ bq,
    const float* __restrict__ Wk, const float* __restrict__ bk,
    const float* __restrict__ Wv, const float* __restrict__ bv,
    uint4* __restrict__ q_pm, uint4* __restrict__ k_pm, uint4* __restrict__ v_pm,
    uint4* __restrict__ xy_pm)
{
    __shared__ ushort sW[80 * 128];    // weights bf16, XOR-swizzled (live whole kernel)
    __shared__ ushort sOut[128 * 88];  // out-tile / xy-tile transpose buffer
    __shared__ float  sb[80];

    const int t = threadIdx.x;

    // ---- stage weights once ----
    for (int i = t; i < 80 * 64; i += 256) {
        int o  = i >> 6;
        int cp = i & 63;
        int c  = cp * 2;
        float w0, w1;
        if (o < 8) {
            if (c < 64) { w0 = Wq[o * 64 + c]; w1 = Wq[o * 64 + c + 1]; }
            else        { w0 = 0.f; w1 = 0.f; }
        } else if (o < 16) {
            if (c >= 64) { w0 = Wk[(o - 8) * 64 + c - 64]; w1 = Wk[(o - 8) * 64 + c - 63]; }
            else         { w0 = 0.f; w1 = 0.f; }
        } else {
            w0 = Wv[(o - 16) * 128 + c];
            w1 = Wv[(o - 16) * 128 + c + 1];
        }
        ((unsigned*)sW)[o * 64 + (cp ^ ((o & 7) << 2))] = pk_bf16(w0, w1);
    }
    if (t < 80) {
        sb[t] = (t < 8) ? bq[t] : (t < 16) ? bk[t - 8] : bv[t - 16];
    }
    __syncthreads();

    const int blk = blockIdx.x;
    const int b   = blk & 7;
    const int p0A = ((blk >> 3) * 2) << 7;    // first tile base
    const int p0B = p0A + 128;                // second tile base

    const int wv = t >> 6, ln = t & 63, lg = ln >> 4, li = ln & 15;

    const float* xb = x + (size_t)b * CDIM * HW;
    const float* yb = y + (size_t)b * CDIM * HW;

    auto load_tile = [&](int p0, bf16x8 (&bx)[2][2], bf16x8 (&by)[2][2],
                         uint4 (&xys)[2][2]) {
        #pragma unroll
        for (int pair = 0; pair < 2; pair++) {
            const int chb = pair * 32 + lg * 8;
            const float* xp = xb + (size_t)chb * HW;
            const float* yp = yb + (size_t)chb * HW;
            #pragma unroll
            for (int n = 0; n < 2; n++) {
                const size_t poff = (size_t)(p0 + wv * 32 + n * 16 + li);
                float fx[8], fy[8];
                #pragma unroll
                for (int e = 0; e < 8; e++) {
                    fx[e] = xp[(size_t)e * HW + poff];
                    fy[e] = yp[(size_t)e * HW + poff];
                }
                uint4 ux, uy, s;
                ux.x = pk_bf16(fx[0], fx[1]); ux.y = pk_bf16(fx[2], fx[3]);
                ux.z = pk_bf16(fx[4], fx[5]); ux.w = pk_bf16(fx[6], fx[7]);
                uy.x = pk_bf16(fy[0], fy[1]); uy.y = pk_bf16(fy[2], fy[3]);
                uy.z = pk_bf16(fy[4], fy[5]); uy.w = pk_bf16(fy[6], fy[7]);
                s.x = pk_bf16(fx[0] + fy[0], fx[1] + fy[1]);
                s.y = pk_bf16(fx[2] + fy[2], fx[3] + fy[3]);
                s.z = pk_bf16(fx[4] + fy[4], fx[5] + fy[5]);
                s.w = pk_bf16(fx[6] + fy[6], fx[7] + fy[7]);
                bx[pair][n] = *(bf16x8*)&ux;
                by[pair][n] = *(bf16x8*)&uy;
                xys[pair][n] = s;
            }
        }
    };

    auto gemm_tile = [&](const bf16x8 (&bx)[2][2], const bf16x8 (&by)[2][2],
                         f32x4 (&acc)[5][2]) {
        #pragma unroll
        for (int pair = 0; pair < 2; pair++) {
            #pragma unroll
            for (int mt = 0; mt < 5; mt++) {
                const int row = mt * 16 + li;
                const int sw  = ((li & 7) << 3);
                bf16x8 ax = *(const bf16x8*)&sW[row * 128 + ((pair * 32 + lg * 8) ^ sw)];
                bf16x8 ay = *(const bf16x8*)&sW[row * 128 + (((2 + pair) * 32 + lg * 8) ^ sw)];
                #pragma unroll
                for (int n = 0; n < 2; n++) {
                    acc[mt][n] = __builtin_amdgcn_mfma_f32_16x16x32_bf16(ax, bx[pair][n], acc[mt][n], 0, 0, 0);
                    acc[mt][n] = __builtin_amdgcn_mfma_f32_16x16x32_bf16(ay, by[pair][n], acc[mt][n], 0, 0, 0);
                }
            }
        }
    };

    auto store_tile = [&](int p0, const f32x4 (&acc)[5][2], const uint4 (&xys)[2][2]) {
        __syncthreads();   // sOut free (prior readers done)
        #pragma unroll
        for (int mt = 0; mt < 5; mt++) {
            const int ob = mt * 16 + lg * 4;
            const float b0 = sb[ob + 0], b1 = sb[ob + 1], b2 = sb[ob + 2], b3 = sb[ob + 3];
            #pragma unroll
            for (int n = 0; n < 2; n++) {
                const int pl = wv * 32 + n * 16 + li;
                uint2 w;
                w.x = pk_bf16(acc[mt][n][0] + b0, acc[mt][n][1] + b1);
                w.y = pk_bf16(acc[mt][n][2] + b2, acc[mt][n][3] + b3);
                *(uint2*)&sOut[pl * 88 + ob] = w;
            }
        }
        __syncthreads();
        const size_t gpb = (size_t)b * HW + p0;
        if (t < 128) {
            q_pm[gpb + t] = *(const uint4*)&sOut[t * 88 + 0];
        } else {
            k_pm[gpb + (t - 128)] = *(const uint4*)&sOut[(t - 128) * 88 + 8];
        }
        #pragma unroll
        for (int i2 = 0; i2 < 4; i2++) {
            const int f = t + i2 * 256;        // 128 pos x 8 uint4
            const int p = f >> 3, q8 = f & 7;
            v_pm[(gpb + p) * 8 + q8] = *(const uint4*)&sOut[p * 88 + 16 + q8 * 8];
        }
        if (xy_pm) {
            __syncthreads();   // sOut becomes xy-tile [pl][72]
            #pragma unroll
            for (int pair = 0; pair < 2; pair++)
                #pragma unroll
                for (int n = 0; n < 2; n++) {
                    const int pl = wv * 32 + n * 16 + li;
                    *(uint4*)&sOut[pl * 72 + pair * 32 + lg * 8] = xys[pair][n];
                }
            __syncthreads();
            #pragma unroll
            for (int i2 = 0; i2 < 4; i2++) {
                const int f = t + i2 * 256;
                const int p = f >> 3, q8 = f & 7;
                xy_pm[(gpb + p) * 8 + q8] = *(const uint4*)&sOut[p * 72 + q8 * 8];
            }
        }
    };

    bf16x8 bxA[2][2], byA[2][2], bxB[2][2], byB[2][2];
    uint4  xyA[2][2], xyB[2][2];
    f32x4  acc[5][2];

    load_tile(p0A, bxA, byA, xyA);

    #pragma unroll
    for (int mt = 0; mt < 5; mt++)
        #pragma unroll
        for (int n = 0; n < 2; n++) acc[mt][n] = (f32x4){0.f, 0.f, 0.f, 0.f};
    gemm_tile(bxA, byA, acc);

    load_tile(p0B, bxB, byB, xyB);    // issued before tile-A stores: latency hides

    store_tile(p0A, acc, xyA);

    #pragma unroll
    for (int mt = 0; mt < 5; mt++)
        #pragma unroll
        for (int n = 0; n < 2; n++) acc[mt][n] = (f32x4){0.f, 0.f, 0.f, 0.f};
    gemm_tile(bxB, byB, acc);

    store_tile(p0B, acc, xyB);
}

// ---------------------------------------------------------------------------
// Kernel 2 (column branch): one block per (b, c).  MFMA tile-GEMMs:
//   QK^T (swapped): D[j][i] = sum_ch K[j][ch] * Q[ch][i]
//   per-row (i) softmax with diag mask, unnormalized
//   PV: D2[ch][i] = sum_j V[ch][j] * P[j][i]
// H_t[b][row=i][col=cc][ch] stored via P_lds-reuse transpose (full-line writes).
// ---------------------------------------------------------------------------
__global__ __launch_bounds__(256, 2) void colattn_kernel(
    const uint4* __restrict__ q_pm, const uint4* __restrict__ k_pm,
    const uint4* __restrict__ v_pm,
    ushort* __restrict__ H_t, float* __restrict__ mH_g, float* __restrict__ sH_g)
{
    __shared__ ushort Q_lds[128 * 8];     // [i][ch]
    __shared__ ushort K_lds[128 * 8];     // [j][ch]
    __shared__ ushort V_lds[64 * 136];    // [ch][j], pad 8
    __shared__ ushort P_lds[128 * 136];   // [i][j], pad 8; reused for H store

    const int blk = blockIdx.x;
    const int b  = blk & 7;
    const int cc = blk >> 3;
    const int t  = threadIdx.x;

    if (t < 128) {
        *(uint4*)&Q_lds[t * 8] = q_pm[(size_t)b * HW + (size_t)t * 128 + cc];
    } else {
        int j = t - 128;
        *(uint4*)&K_lds[j * 8] = k_pm[(size_t)b * HW + (size_t)j * 128 + cc];
    }
    {
        int j = t & 127, h = t >> 7;
        const uint4* vp = v_pm + ((size_t)b * HW + (size_t)j * 128 + cc) * 8 + 4 * h;
        #pragma unroll
        for (int qd = 0; qd < 4; qd++) {
            uint4 vu = vp[qd];
            int ch0 = 32 * h + 8 * qd;
            V_lds[(ch0 + 0) * 136 + j] = (ushort)(vu.x & 0xffff);
            V_lds[(ch0 + 1) * 136 + j] = (ushort)(vu.x >> 16);
            V_lds[(ch0 + 2) * 136 + j] = (ushort)(vu.y & 0xffff);
            V_lds[(ch0 + 3) * 136 + j] = (ushort)(vu.y >> 16);
            V_lds[(ch0 + 4) * 136 + j] = (ushort)(vu.z & 0xffff);
            V_lds[(ch0 + 5) * 136 + j] = (ushort)(vu.z >> 16);
            V_lds[(ch0 + 6) * 136 + j] = (ushort)(vu.w & 0xffff);
            V_lds[(ch0 + 7) * 136 + j] = (ushort)(vu.w >> 16);
        }
    }
    __syncthreads();

    const int wv = t >> 6, ln = t & 63, lg = ln >> 4, li = ln & 15;
    const bf16x8 zf = {0, 0, 0, 0, 0, 0, 0, 0};

    // ---- QK^T ----
    bf16x8 afr[8], bfr[2];
    #pragma unroll
    for (int jt = 0; jt < 8; jt++)
        afr[jt] = (lg == 0) ? *(const bf16x8*)&K_lds[(jt * 16 + li) * 8] : zf;
    #pragma unroll
    for (int it2 = 0; it2 < 2; it2++)
        bfr[it2] = (lg == 0) ? *(const bf16x8*)&Q_lds[((2 * wv + it2) * 16 + li) * 8] : zf;

    f32x4 dfr[2][8];
    #pragma unroll
    for (int a = 0; a < 2; a++)
        #pragma unroll
        for (int jt = 0; jt < 8; jt++) dfr[a][jt] = (f32x4){0.f, 0.f, 0.f, 0.f};

    #pragma unroll
    for (int it2 = 0; it2 < 2; it2++)
        #pragma unroll
        for (int jt = 0; jt < 8; jt++)
            dfr[it2][jt] = __builtin_amdgcn_mfma_f32_16x16x32_bf16(
                afr[jt], bfr[it2], dfr[it2][jt], 0, 0, 0);

    // ---- softmax (unnormalized, diag masked) ----
    #pragma unroll
    for (int it2 = 0; it2 < 2; it2++) {
        const int i = (2 * wv + it2) * 16 + li;
        float m = -1e30f;
        #pragma unroll
        for (int jt = 0; jt < 8; jt++)
            #pragma unroll
            for (int rr = 0; rr < 4; rr++) {
                int j = jt * 16 + lg * 4 + rr;
                float e = dfr[it2][jt][rr];
                if (j == i) e = -1e30f;
                dfr[it2][jt][rr] = e;
                m = fmaxf(m, e);
            }
        m = fmaxf(m, __shfl_xor(m, 16));
        m = fmaxf(m, __shfl_xor(m, 32));
        float s = 0.f;
        #pragma unroll
        for (int jt = 0; jt < 8; jt++)
            #pragma unroll
            for (int rr = 0; rr < 4; rr++) {
                float p = __expf(dfr[it2][jt][rr] - m);
                dfr[it2][jt][rr] = p;
                s += p;
            }
        s += __shfl_xor(s, 16);
        s += __shfl_xor(s, 32);
        #pragma unroll
        for (int jt = 0; jt < 8; jt++) {
            uint2 w;
            w.x = pk_bf16(dfr[it2][jt][0], dfr[it2][jt][1]);
            w.y = pk_bf16(dfr[it2][jt][2], dfr[it2][jt][3]);
            *(uint2*)&P_lds[(size_t)i * 136 + jt * 16 + lg * 4] = w;
        }
        if (lg == 0) {
            mH_g[((size_t)b * 128 + cc) * 128 + i] = m;
            sH_g[((size_t)b * 128 + cc) * 128 + i] = s;
        }
    }
    __syncthreads();

    // ---- PV ----
    f32x4 ofr[8];
    #pragma unroll
    for (int itl = 0; itl < 8; itl++) ofr[itl] = (f32x4){0.f, 0.f, 0.f, 0.f};

    #pragma unroll
    for (int ks = 0; ks < 4; ks++) {
        const int jb = ks * 32 + lg * 8;
        bf16x8 av = *(const bf16x8*)&V_lds[(wv * 16 + li) * 136 + jb];
        #pragma unroll
        for (int itl = 0; itl < 8; itl++) {
            bf16x8 bp = *(const bf16x8*)&P_lds[(itl * 16 + li) * 136 + jb];
            ofr[itl] = __builtin_amdgcn_mfma_f32_16x16x32_bf16(av, bp, ofr[itl], 0, 0, 0);
        }
    }
    __syncthreads();   // P_lds dead; reuse as H transpose buffer [128][72]

    #pragma unroll
    for (int itl = 0; itl < 8; itl++) {
        const int i = itl * 16 + li;
        uint2 w;
        w.x = pk_bf16(ofr[itl][0], ofr[itl][1]);
        w.y = pk_bf16(ofr[itl][2], ofr[itl][3]);
        *(uint2*)&P_lds[i * 72 + wv * 16 + lg * 4] = w;
    }
    __syncthreads();

    #pragma unroll
    for (int i2 = 0; i2 < 4; i2++) {
        const int f = t + i2 * 256;          // 128 i x 8 chunks
        const int i = f >> 3, cb = (f & 7) * 8;
        *(uint4*)&H_t[(((size_t)b * 128 + i) * 128 + cc) * 64 + cb] =
            *(const uint4*)&P_lds[i * 72 + cb];
    }
}

// ---------------------------------------------------------------------------
// Kernel 3 (row branch + merge): one block per (b, r).  Same GEMM structure
// (no diag mask); epilogue merges with the column branch (mH/sH/H_t) and adds
// the residual:  out = (H*wH + W*wW) * gamma/(sH*wH + sW*wW) + (x + y).
// USE_XY: residual from bf16 xy_pm (written by qkv) instead of fp32 x,y.
// ---------------------------------------------------------------------------
template<int USE_XY>
__global__ __launch_bounds__(256, 2) void rowattn_kernel(
    const uint4* __restrict__ q_pm, const uint4* __restrict__ k_pm,
    const uint4* __restrict__ v_pm,
    const ushort* __restrict__ H_t, const float* __restrict__ mH_g,
    const float* __restrict__ sH_g,
    const float* __restrict__ x, const float* __restrict__ y,
    const ushort* __restrict__ xy_pm,
    const float* __restrict__ gptr, float* __restrict__ out)
{
    __shared__ ushort Q_lds[128 * 8];     // [i][ch]  (i = column index)
    __shared__ ushort K_lds[128 * 8];     // [j][ch]
    __shared__ ushort V_lds[64 * 136];    // [ch][j]
    __shared__ ushort P_lds[128 * 136];   // [i][j]
    __shared__ float mW_s[128], sW_s[128];

    const int blk = blockIdx.x;
    const int b = blk & 7;
    const int r = blk >> 3;
    const int t = threadIdx.x;

    if (t < 128) {
        *(uint4*)&Q_lds[t * 8] = q_pm[(size_t)b * HW + (size_t)r * 128 + t];
    } else {
        int j = t - 128;
        *(uint4*)&K_lds[j * 8] = k_pm[(size_t)b * HW + (size_t)r * 128 + j];
    }
    {
        int j = t & 127, h = t >> 7;
        const uint4* vp = v_pm + ((size_t)b * HW + (size_t)r * 128 + j) * 8 + 4 * h;
        #pragma unroll
        for (int qd = 0; qd < 4; qd++) {
            uint4 vu = vp[qd];
            int ch0 = 32 * h + 8 * qd;
            V_lds[(ch0 + 0) * 136 + j] = (ushort)(vu.x & 0xffff);
            V_lds[(ch0 + 1) * 136 + j] = (ushort)(vu.x >> 16);
            V_lds[(ch0 + 2) * 136 + j] = (ushort)(vu.y & 0xffff);
            V_lds[(ch0 + 3) * 136 + j] = (ushort)(vu.y >> 16);
            V_lds[(ch0 + 4) * 136 + j] = (ushort)(vu.z & 0xffff);
            V_lds[(ch0 + 5) * 136 + j] = (ushort)(vu.z >> 16);
            V_lds[(ch0 + 6) * 136 + j] = (ushort)(vu.w & 0xffff);
            V_lds[(ch0 + 7) * 136 + j] = (ushort)(vu.w >> 16);
        }
    }
    __syncthreads();

    const int wv = t >> 6, ln = t & 63, lg = ln >> 4, li = ln & 15;
    const bf16x8 zf = {0, 0, 0, 0, 0, 0, 0, 0};

    bf16x8 afr[8], bfr[2];
    #pragma unroll
    for (int jt = 0; jt < 8; jt++)
        afr[jt] = (lg == 0) ? *(const bf16x8*)&K_lds[(jt * 16 + li) * 8] : zf;
    #pragma unroll
    for (int it2 = 0; it2 < 2; it2++)
        bfr[it2] = (lg == 0) ? *(const bf16x8*)&Q_lds[((2 * wv + it2) * 16 + li) * 8] : zf;

    f32x4 dfr[2][8];
    #pragma unroll
    for (int a = 0; a < 2; a++)
        #pragma unroll
        for (int jt = 0; jt < 8; jt++) dfr[a][jt] = (f32x4){0.f, 0.f, 0.f, 0.f};

    #pragma unroll
    for (int it2 = 0; it2 < 2; it2++)
        #pragma unroll
        for (int jt = 0; jt < 8; jt++)
            dfr[it2][jt] = __builtin_amdgcn_mfma_f32_16x16x32_bf16(
                afr[jt], bfr[it2], dfr[it2][jt], 0, 0, 0);

    #pragma unroll
    for (int it2 = 0; it2 < 2; it2++) {
        const int i = (2 * wv + it2) * 16 + li;
        float m = -1e30f;
        #pragma unroll
        for (int jt = 0; jt < 8; jt++)
            #pragma unroll
            for (int rr = 0; rr < 4; rr++)
                m = fmaxf(m, dfr[it2][jt][rr]);
        m = fmaxf(m, __shfl_xor(m, 16));
        m = fmaxf(m, __shfl_xor(m, 32));
        float s = 0.f;
        #pragma unroll
        for (int jt = 0; jt < 8; jt++)
            #pragma unroll
            for (int rr = 0; rr < 4; rr++) {
                float p = __expf(dfr[it2][jt][rr] - m);
                dfr[it2][jt][rr] = p;
                s += p;
            }
        s += __shfl_xor(s, 16);
        s += __shfl_xor(s, 32);
        #pragma unroll
        for (int jt = 0; jt < 8; jt++) {
            uint2 w;
            w.x = pk_bf16(dfr[it2][jt][0], dfr[it2][jt][1]);
            w.y = pk_bf16(dfr[it2][jt][2], dfr[it2][jt][3]);
            *(uint2*)&P_lds[(size_t)i * 136 + jt * 16 + lg * 4] = w;
        }
        if (lg == 0) {
            mW_s[i] = m;
            sW_s[i] = s;
        }
    }
    __syncthreads();

    f32x4 ofr[8];
    #pragma unroll
    for (int itl = 0; itl < 8; itl++) ofr[itl] = (f32x4){0.f, 0.f, 0.f, 0.f};

    #pragma unroll
    for (int ks = 0; ks < 4; ks++) {
        const int jb = ks * 32 + lg * 8;
        bf16x8 av = *(const bf16x8*)&V_lds[(wv * 16 + li) * 136 + jb];
        #pragma unroll
        for (int itl = 0; itl < 8; itl++) {
            bf16x8 bp = *(const bf16x8*)&P_lds[(itl * 16 + li) * 136 + jb];
            ofr[itl] = __builtin_amdgcn_mfma_f32_16x16x32_bf16(av, bp, ofr[itl], 0, 0, 0);
        }
    }

    const float gamma = gptr[0];
    #pragma unroll
    for (int itl = 0; itl < 8; itl++) {
        const int i = itl * 16 + li;     // column index of this position
        float mWv = mW_s[i], sWv = sW_s[i];
        float mHv = mH_g[((size_t)b * 128 + i) * 128 + r];
        float sHv = sH_g[((size_t)b * 128 + i) * 128 + r];
        float m  = fmaxf(mHv, mWv);
        float wH = __expf(mHv - m);
        float wW = __expf(mWv - m);
        float invg = gamma / (sHv * wH + sWv * wW);

        // coalesced-footprint H read: [b][r][i][ch], 8B per lane per itl
        uint2 hw = *(const uint2*)&H_t[(((size_t)b * 128 + r) * 128 + i) * 64 + wv * 16 + lg * 4];
        float h[4];
        cvt2(hw.x, h[0], h[1]);
        cvt2(hw.y, h[2], h[3]);

        float resid[4];
        if (USE_XY) {
            uint2 xu = *(const uint2*)&xy_pm[((size_t)b * HW + (size_t)r * 128 + i) * 64 + wv * 16 + lg * 4];
            cvt2(xu.x, resid[0], resid[1]);
            cvt2(xu.y, resid[2], resid[3]);
        }

        #pragma unroll
        for (int rr = 0; rr < 4; rr++) {
            const int ch = wv * 16 + lg * 4 + rr;
            size_t o = (((size_t)b * 64 + ch) * 128 + r) * 128 + i;
            float res = USE_XY ? resid[rr] : (x[o] + y[o]);
            out[o] = (h[rr] * wH + ofr[itl][rr] * wW) * invg + res;
        }
    }
}

// ---------------------------------------------------------------------------
extern "C" void kernel_launch(void* const* d_in, const int* in_sizes, int n_in,
                              void* d_out, int out_size, void* d_ws, size_t ws_size,
                              hipStream_t stream)
{
    const float* x     = (const float*)d_in[0];
    const float* y     = (const float*)d_in[1];
    const float* Wq    = (const float*)d_in[2];
    const float* bq    = (const float*)d_in[3];
    const float* Wk    = (const float*)d_in[4];
    const float* bk    = (const float*)d_in[5];
    const float* Wv    = (const float*)d_in[6];
    const float* bv    = (const float*)d_in[7];
    const float* gamma = (const float*)d_in[8];
    float* out = (float*)d_out;

    // Workspace: q 2MB | k 2MB | v 16MB | H_t 16MB | mH .5MB | sH .5MB | xy 16MB
    uint4*  q_pm = (uint4*)d_ws;                        // 131072 uint4
    uint4*  k_pm = q_pm + (size_t)BDIM * HW;            // 131072 uint4
    uint4*  v_pm = k_pm + (size_t)BDIM * HW;            // 1048576 uint4
    ushort* H_t  = (ushort*)(v_pm + (size_t)BDIM * HW * 8);      // 8388608 us
    float*  mH   = (float*)(H_t + (size_t)BDIM * HW * 64);
    float*  sH   = mH + (size_t)BDIM * HW;
    ushort* xy   = (ushort*)(sH + (size_t)BDIM * HW);            // 8388608 us
    size_t need  = (size_t)((char*)(xy + (size_t)BDIM * HW * 64) - (char*)d_ws);
    const bool use_xy = ws_size >= need;

    // 512 blocks: (b = blk&7, 2 consecutive 128-position tiles per block)
    qkv_kernel<<<dim3(BDIM * HW / 256), dim3(256), 0, stream>>>(
        x, y, Wq, bq, Wk, bk, Wv, bv, q_pm, k_pm, v_pm,
        use_xy ? (uint4*)xy : (uint4*)nullptr);

    colattn_kernel<<<dim3(BDIM * WDIM), dim3(256), 0, stream>>>(
        q_pm, k_pm, v_pm, H_t, mH, sH);

    if (use_xy) {
        rowattn_kernel<1><<<dim3(BDIM * HDIM), dim3(256), 0, stream>>>(
            q_pm, k_pm, v_pm, H_t, mH, sH, x, y, xy, gamma, out);
    } else {
        rowattn_kernel<0><<<dim3(BDIM * HDIM), dim3(256), 0, stream>>>(
            q_pm, k_pm, v_pm, H_t, mH, sH, x, y, xy, gamma, out);
    }
}